// Round 7
// baseline (377.222 us; speedup 1.0000x reference)
//
#include <hip/hip_runtime.h>

#define T_LEN 256
#define D_IN 4
#define HID 16

typedef _Float16 half8 __attribute__((ext_vector_type(8)));
typedef _Float16 half4v __attribute__((ext_vector_type(4)));
typedef float float4v __attribute__((ext_vector_type(4)));

struct CellW { const float *Wih, *Whh, *bih, *bhh; };
struct Params { CellW c[6]; const float* y; float* hout; };

__device__ __forceinline__ float fexp2(float x) { return __builtin_amdgcn_exp2f(x); }
__device__ __forceinline__ float frcp(float x)  { return __builtin_amdgcn_rcpf(x); }

#define SCHED_FENCE() asm volatile("" ::: "memory")
#define MFMA(a, b, c) __builtin_amdgcn_mfma_f32_16x16x32_f16(a, b, c, 0, 0, 0)

// D regs hold -log2e-scaled preacts (g gate: -2log2e). Lane: units 4q+r, batch n.
__device__ __forceinline__ void cell_act(const float4v& pi, const float4v& pf,
                                         const float4v& pg, const float4v& po,
                                         float4v& c, float h[4]) {
#pragma unroll
    for (int r = 0; r < 4; ++r) {
        float i = frcp(1.f + fexp2(pi[r]));
        float f = frcp(1.f + fexp2(pf[r]));
        float g = fmaf(2.f, frcp(1.f + fexp2(pg[r])), -1.f);
        float o = frcp(1.f + fexp2(po[r]));
        float cn = fmaf(f, c[r], i * g);
        c[r] = cn;
        float th = fmaf(-2.f, frcp(1.f + fexp2(cn * 2.8853900817779268f)), 1.f);
        h[r] = o * th;
    }
}

// LDS (halfs): ZP[0..255]=zeros, H1@256, H2@512, H3@768 — all [batch][unit].
__global__ void __launch_bounds__(64)
__attribute__((amdgpu_waves_per_eu(1, 2)))
lstm_chain_kernel(Params p)
{
    __shared__ _Float16 lds[1024];

    const int L    = threadIdx.x & 63;
    const int tid  = blockIdx.x;
    const int dir  = tid & 1;
    const int b0   = (tid >> 1) * 16;
    const int n    = L & 15;     // A: unit row / B,D: batch col
    const int quad = L >> 4;

    const CellW c1 = p.c[dir * 3 + 0];
    const CellW c2 = p.c[dir * 3 + 1];
    const CellW c3 = p.c[dir * 3 + 2];
    const float LOG2E = 1.4426950408889634f;

    // ---- A-frags: A[u=n][k=quad*8+j] = W[g*16+u][k], scale folded ----
    half8 A1[4], A2[4], A3[4];
    float4v bs1[4], bs2[4], bs3[4];
#pragma unroll
    for (int g = 0; g < 4; ++g) {
        const float s = (g == 2) ? -2.f * LOG2E : -LOG2E;
        const int row = g * 16 + n;
        half8 a;
#pragma unroll
        for (int j = 0; j < 8; ++j) {       // cell1: k<4 Wih(4-wide), 4..15 zero, 16.. Whh
            int k = quad * 8 + j; float v;
            if (k < D_IN)       v = c1.Wih[row * D_IN + k];
            else if (k < 16)    v = 0.f;
            else                v = c1.Whh[row * 16 + (k - 16)];
            a[j] = (_Float16)(v * s);
        }
        A1[g] = a;
#pragma unroll
        for (int j = 0; j < 8; ++j) {
            int k = quad * 8 + j;
            float v = (k < 16) ? c2.Wih[row * 16 + k] : c2.Whh[row * 16 + (k - 16)];
            a[j] = (_Float16)(v * s);
        }
        A2[g] = a;
#pragma unroll
        for (int j = 0; j < 8; ++j) {
            int k = quad * 8 + j;
            float v = (k < 16) ? c3.Wih[row * 16 + k] : c3.Whh[row * 16 + (k - 16)];
            a[j] = (_Float16)(v * s);
        }
        A3[g] = a;
        // bias C-operand: reg r -> unit 4*quad+r
        const int u0 = g * 16 + 4 * quad;
        float4 bi1 = *(const float4*)&c1.bih[u0], bh1 = *(const float4*)&c1.bhh[u0];
        float4 bi2 = *(const float4*)&c2.bih[u0], bh2 = *(const float4*)&c2.bhh[u0];
        float4 bi3 = *(const float4*)&c3.bih[u0], bh3 = *(const float4*)&c3.bhh[u0];
        bs1[g] = (float4v){(bi1.x+bh1.x)*s, (bi1.y+bh1.y)*s, (bi1.z+bh1.z)*s, (bi1.w+bh1.w)*s};
        bs2[g] = (float4v){(bi2.x+bh2.x)*s, (bi2.y+bh2.y)*s, (bi2.z+bh2.z)*s, (bi2.w+bh2.w)*s};
        bs3[g] = (float4v){(bi3.x+bh3.x)*s, (bi3.y+bh3.y)*s, (bi3.z+bh3.z)*s, (bi3.w+bh3.w)*s};
    }

    // ---- LDS addresses (half indices) ----
    const int col = n * 16;
    const int rd1 = (quad < 2) ? (0   + col + quad * 8) : (256 + col + (quad - 2) * 8);
    const int rd2 = (quad < 2) ? (256 + col + quad * 8) : (512 + col + (quad - 2) * 8);
    const int rd3 = (quad < 2) ? (512 + col + quad * 8) : (768 + col + (quad - 2) * 8);
    const int wr1 = 256 + col + 4 * quad;
    const int wr2 = 512 + col + 4 * quad;
    const int wr3 = 768 + col + 4 * quad;

    // ---- zero LDS (ZP + H slabs: h(-1)=0), load x(0) ----
    {
        int* l4 = (int*)lds;
#pragma unroll
        for (int i = 0; i < 8; ++i) l4[L + 64 * i] = 0;
    }
    SCHED_FENCE();
    const float* ybase = p.y + (size_t)b0 * (T_LEN * D_IN);
    float4 xv = {0.f, 0.f, 0.f, 0.f};
    const int tt0 = dir ? (T_LEN - 1) : 0;
    if (L < 16) xv = *(const float4*)(ybase + ((size_t)L * T_LEN + tt0) * D_IN);

    // b1 for t=0: zeros + x injected into quad0 (k=0..3)
    half8 b1;
    {
        int4 z = *(const int4*)&lds[rd1];   // zeros
        half4v xh = {(_Float16)xv.x, (_Float16)xv.y, (_Float16)xv.z, (_Float16)xv.w};
        int2 xw = __builtin_bit_cast(int2, xh);
        if (quad == 0) { z.x = xw.x; z.y = xw.y; }
        b1 = __builtin_bit_cast(half8, z);
    }

    float4v cc1 = {0.f,0.f,0.f,0.f}, cc2 = {0.f,0.f,0.f,0.f}, cc3 = {0.f,0.f,0.f,0.f};
    float h1[4], h2[4], h3[4];

#pragma unroll 1
    for (int t = 0; t < T_LEN; ++t) {
        // prefetch x(t+1): consumed only at loop end -> vmcnt fully hidden
        const int tn  = (t + 1 < T_LEN) ? (t + 1) : (T_LEN - 1);
        const int ttn = dir ? (T_LEN - 1 - tn) : tn;
        float4 xn = {0.f, 0.f, 0.f, 0.f};
        if (L < 16) xn = *(const float4*)(ybase + ((size_t)L * T_LEN + ttn) * D_IN);

        // ---- cell 1 ----
        {
            float4v gi = MFMA(A1[0], b1, bs1[0]);
            float4v gf = MFMA(A1[1], b1, bs1[1]);
            float4v gg = MFMA(A1[2], b1, bs1[2]);
            float4v go = MFMA(A1[3], b1, bs1[3]);
            cell_act(gi, gf, gg, go, cc1, h1);
        }
        {
            half4v hv = {(_Float16)h1[0], (_Float16)h1[1], (_Float16)h1[2], (_Float16)h1[3]};
            *(int2*)&lds[wr1] = __builtin_bit_cast(int2, hv);
        }
        SCHED_FENCE();
        int4 t2  = *(const int4*)&lds[rd2];   // [h1 new | h2 old]
        int4 t1n = *(const int4*)&lds[rd1];   // h1 new (quads 2,3) for t+1
        SCHED_FENCE();

        // ---- cell 2 ----
        {
            half8 b2 = __builtin_bit_cast(half8, t2);
            float4v gi = MFMA(A2[0], b2, bs2[0]);
            float4v gf = MFMA(A2[1], b2, bs2[1]);
            float4v gg = MFMA(A2[2], b2, bs2[2]);
            float4v go = MFMA(A2[3], b2, bs2[3]);
            cell_act(gi, gf, gg, go, cc2, h2);
        }
        {
            half4v hv = {(_Float16)h2[0], (_Float16)h2[1], (_Float16)h2[2], (_Float16)h2[3]};
            *(int2*)&lds[wr2] = __builtin_bit_cast(int2, hv);
        }
        SCHED_FENCE();
        int4 t3 = *(const int4*)&lds[rd3];    // [h2 new | h3 old]
        SCHED_FENCE();

        // ---- cell 3 ----
        {
            half8 b3 = __builtin_bit_cast(half8, t3);
            float4v gi = MFMA(A3[0], b3, bs3[0]);
            float4v gf = MFMA(A3[1], b3, bs3[1]);
            float4v gg = MFMA(A3[2], b3, bs3[2]);
            float4v go = MFMA(A3[3], b3, bs3[3]);
            cell_act(gi, gf, gg, go, cc3, h3);
        }
        {
            half4v hv = {(_Float16)h3[0], (_Float16)h3[1], (_Float16)h3[2], (_Float16)h3[3]};
            *(int2*)&lds[wr3] = __builtin_bit_cast(int2, hv);
        }
        SCHED_FENCE();

        // ---- b1 for t+1: [x(t+1) | h1(t)] ----
        {
            half4v xh = {(_Float16)xn.x, (_Float16)xn.y, (_Float16)xn.z, (_Float16)xn.w};
            int2 xw = __builtin_bit_cast(int2, xh);
            int4 nb = t1n;
            if (quad == 0) { nb.x = xw.x; nb.y = xw.y; }
            b1 = __builtin_bit_cast(half8, nb);
        }
    }

    // lane holds h3[u=4q+r][batch n] -> hout[(b0+n)*32 + dir*16 + 4q + r]
    {
        float4v ho = {h3[0], h3[1], h3[2], h3[3]};
        *(float4v*)&p.hout[(size_t)(b0 + n) * 32 + dir * HID + 4 * quad] = ho;
    }
}

__global__ void out_proj_kernel(const float* __restrict__ ws,
                                const float* __restrict__ Wout,
                                const float* __restrict__ bout,
                                float* __restrict__ out, int B)
{
    int idx = blockIdx.x * blockDim.x + threadIdx.x;
    if (idx >= B * 4) return;
    int b = idx >> 2, o = idx & 3;
    float acc = bout[o];
    const float* h = ws + (size_t)b * 32;
    const float* w = Wout + o * 32;
#pragma unroll
    for (int m = 0; m < 32; ++m) acc = fmaf(h[m], w[m], acc);
    out[idx] = acc;
}

extern "C" void kernel_launch(void* const* d_in, const int* in_sizes, int n_in,
                              void* d_out, int out_size, void* d_ws, size_t ws_size,
                              hipStream_t stream)
{
    const int B = in_sizes[0] / (T_LEN * D_IN); // 4096

    Params p;
    for (int s = 0; s < 6; ++s) {
        p.c[s].Wih = (const float*)d_in[1 + 4 * s];
        p.c[s].Whh = (const float*)d_in[2 + 4 * s];
        p.c[s].bih = (const float*)d_in[3 + 4 * s];
        p.c[s].bhh = (const float*)d_in[4 + 4 * s];
    }
    p.y = (const float*)d_in[0];
    p.hout = (float*)d_ws;

    const int tiles = (B / 16) * 2;          // 16 chains per wave, both dirs
    lstm_chain_kernel<<<tiles, 64, 0, stream>>>(p);

    const float* Wout = (const float*)d_in[25];
    const float* bout = (const float*)d_in[26];
    out_proj_kernel<<<(B * 4 + 255) / 256, 256, 0, stream>>>(
        (const float*)d_ws, Wout, bout, (float*)d_out, B);
}

// Round 8
// 352.556 us; speedup vs baseline: 1.0700x; 1.0700x over previous
//
#include <hip/hip_runtime.h>

#define T_LEN 256
#define D_IN 4
#define HID 16

typedef _Float16 half8 __attribute__((ext_vector_type(8)));
typedef __fp16 cvt2_t __attribute__((ext_vector_type(2)));
typedef float float4v __attribute__((ext_vector_type(4)));

struct CellW { const float *Wih, *Whh, *bih, *bhh; };
struct Params { CellW c[6]; const float* y; float* hout; };

__device__ __forceinline__ float fexp2(float x) { return __builtin_amdgcn_exp2f(x); }
__device__ __forceinline__ float frcp(float x)  { return __builtin_amdgcn_rcpf(x); }
__device__ __forceinline__ int bperm(int a, int v) { return __builtin_amdgcn_ds_bpermute(a, v); }
__device__ __forceinline__ int packh(float a, float b) {
    cvt2_t p = __builtin_amdgcn_cvt_pkrtz(a, b);
    return __builtin_bit_cast(int, p);
}

#define MFMA(a, b, c) __builtin_amdgcn_mfma_f32_16x16x32_f16(a, b, c, 0, 0, 0)

// preacts are -log2e-scaled (g gate: -2log2e), scale folded into A/bias.
__device__ __forceinline__ void cell_act(const float4v& pi, const float4v& pf,
                                         const float4v& pg, const float4v& po,
                                         float4v& c, float h[4]) {
#pragma unroll
    for (int r = 0; r < 4; ++r) {
        float i = frcp(1.f + fexp2(pi[r]));
        float f = frcp(1.f + fexp2(pf[r]));
        float g = fmaf(2.f, frcp(1.f + fexp2(pg[r])), -1.f);
        float o = frcp(1.f + fexp2(po[r]));
        float cn = fmaf(f, c[r], i * g);
        c[r] = cn;
        float th = fmaf(-2.f, frcp(1.f + fexp2(cn * 2.8853900817779268f)), 1.f);
        h[r] = o * th;
    }
}

// One cell step: 4 gate MFMAs, activation, pack h, bpermute-gather into g[4].
// g serves (a) next layer's B input part (Q<2) and (b) this cell's own
// recurrence part (Q>=2) next timestep — same 4 dwords for both.
__device__ __forceinline__ void do_cell(const half8* A, const float4v* bs,
                                        int bd0, int bd1, int bd2, int bd3,
                                        float4v& c, int g[4], int aL, int aH,
                                        float h[4]) {
    int4 bi = {bd0, bd1, bd2, bd3};
    half8 b = __builtin_bit_cast(half8, bi);
    float4v pi = MFMA(A[0], b, bs[0]);
    float4v pf = MFMA(A[1], b, bs[1]);
    float4v pg = MFMA(A[2], b, bs[2]);
    float4v po = MFMA(A[3], b, bs[3]);
    cell_act(pi, pf, pg, po, c, h);
    int d0 = packh(h[0], h[1]);
    int d1 = packh(h[2], h[3]);
    g[0] = bperm(aL, d0);
    g[1] = bperm(aL, d1);
    g[2] = bperm(aH, d0);
    g[3] = bperm(aH, d1);
}

__global__ void __launch_bounds__(64)
__attribute__((amdgpu_waves_per_eu(1, 2)))
lstm_chain_kernel(Params p)
{
    const int L   = threadIdx.x & 63;
    const int tid = blockIdx.x;
    const int dir = tid & 1;
    const int b0  = (tid >> 1) * 16;
    const int n   = L & 15;      // A: unit row / B,D: batch col
    const int Q   = L >> 4;

    const CellW c1w = p.c[dir * 3 + 0];
    const CellW c2w = p.c[dir * 3 + 1];
    const CellW c3w = p.c[dir * 3 + 2];
    const float LOG2E = 1.4426950408889634f;

    // ---- A-frags: A[u=n][k=Q*8+j] = W[g*16+u][k], activation scale folded ----
    half8 A1[4], A2[4], A3[4];
    float4v bs1[4], bs2[4], bs3[4];
#pragma unroll
    for (int g = 0; g < 4; ++g) {
        const float s = (g == 2) ? -2.f * LOG2E : -LOG2E;
        const int row = g * 16 + n;
        half8 a;
#pragma unroll
        for (int j = 0; j < 8; ++j) {   // cell1: k<4 Wih, 4..15 zero, 16.. Whh
            int k = Q * 8 + j; float v;
            if (k < D_IN)    v = c1w.Wih[row * D_IN + k];
            else if (k < 16) v = 0.f;
            else             v = c1w.Whh[row * 16 + (k - 16)];
            a[j] = (_Float16)(v * s);
        }
        A1[g] = a;
#pragma unroll
        for (int j = 0; j < 8; ++j) {
            int k = Q * 8 + j;
            float v = (k < 16) ? c2w.Wih[row * 16 + k] : c2w.Whh[row * 16 + (k - 16)];
            a[j] = (_Float16)(v * s);
        }
        A2[g] = a;
#pragma unroll
        for (int j = 0; j < 8; ++j) {
            int k = Q * 8 + j;
            float v = (k < 16) ? c3w.Wih[row * 16 + k] : c3w.Whh[row * 16 + (k - 16)];
            a[j] = (_Float16)(v * s);
        }
        A3[g] = a;
        const int u0 = g * 16 + 4 * Q;   // bias: reg r -> unit 4Q+r
        float4 bi1 = *(const float4*)&c1w.bih[u0], bh1 = *(const float4*)&c1w.bhh[u0];
        float4 bi2 = *(const float4*)&c2w.bih[u0], bh2 = *(const float4*)&c2w.bhh[u0];
        float4 bi3 = *(const float4*)&c3w.bih[u0], bh3 = *(const float4*)&c3w.bhh[u0];
        bs1[g] = (float4v){(bi1.x+bh1.x)*s, (bi1.y+bh1.y)*s, (bi1.z+bh1.z)*s, (bi1.w+bh1.w)*s};
        bs2[g] = (float4v){(bi2.x+bh2.x)*s, (bi2.y+bh2.y)*s, (bi2.z+bh2.z)*s, (bi2.w+bh2.w)*s};
        bs3[g] = (float4v){(bi3.x+bh3.x)*s, (bi3.y+bh3.y)*s, (bi3.z+bh3.z)*s, (bi3.w+bh3.w)*s};
    }

    // bpermute source-lane addresses (bytes = 4*lane)
    const int aL = 4 * ((Q & 1) * 32 + n);
    const int aH = aL + 64;

    float4v cc1 = {0,0,0,0}, cc2 = {0,0,0,0}, cc3 = {0,0,0,0};
    int g1[4] = {0,0,0,0}, g2[4] = {0,0,0,0}, g3[4] = {0,0,0,0};
    float h1o[4], h2o[4], h3o[4];

    const float* ybase = p.y + (size_t)b0 * (T_LEN * D_IN);
    auto ldx = [&](int t) -> float4 {
        float4 r = {0.f, 0.f, 0.f, 0.f};
        const int tt = dir ? (T_LEN - 1 - t) : t;
        if (L < 16) r = *(const float4*)(ybase + ((size_t)L * T_LEN + tt) * D_IN);
        return r;
    };

    // ---------- prologue (pipeline fill): cell1(0); cell2(0),cell1(1) ----------
    {
        float4 x = ldx(0);
        int xp0 = packh(x.x, x.y), xp1 = packh(x.z, x.w);
        do_cell(A1, bs1, (Q==0)?xp0:0, (Q==0)?xp1:0, 0, 0, cc1, g1, aL, aH, h1o);
    }
    {
        float4 x = ldx(1);
        int xp0 = packh(x.x, x.y), xp1 = packh(x.z, x.w);
        int b20 = (Q<2)?g1[0]:g2[0], b21 = (Q<2)?g1[1]:g2[1];
        int b22 = (Q<2)?g1[2]:g2[2], b23 = (Q<2)?g1[3]:g2[3];
        do_cell(A2, bs2, b20, b21, b22, b23, cc2, g2, aL, aH, h2o);
        int b10 = (Q==0)?xp0:((Q>=2)?g1[0]:0);
        int b11 = (Q==0)?xp1:((Q>=2)?g1[1]:0);
        int b12 = (Q>=2)?g1[2]:0, b13 = (Q>=2)?g1[3]:0;
        do_cell(A1, bs1, b10, b11, b12, b13, cc1, g1, aL, aH, h1o);
    }

    // ---------- main skewed loop: i=2..255 -> cell3(i-2), cell2(i-1), cell1(i) ----------
    float4 xc = ldx(2);                  // x for cell1 of this iteration
    float4 xf = ldx(3);                  // one ahead
#pragma unroll 1
    for (int i = 2; i < T_LEN; ++i) {
        const int tpre = (i + 2 < T_LEN) ? (i + 2) : (T_LEN - 1);
        float4 xn = ldx(tpre);
        int xp0 = packh(xc.x, xc.y), xp1 = packh(xc.z, xc.w);

        // B-builds read OLD g's (all three cells mutually independent)
        int b30 = (Q<2)?g2[0]:g3[0], b31 = (Q<2)?g2[1]:g3[1];
        int b32 = (Q<2)?g2[2]:g3[2], b33 = (Q<2)?g2[3]:g3[3];
        int b20 = (Q<2)?g1[0]:g2[0], b21 = (Q<2)?g1[1]:g2[1];
        int b22 = (Q<2)?g1[2]:g2[2], b23 = (Q<2)?g1[3]:g2[3];
        int b10 = (Q==0)?xp0:((Q>=2)?g1[0]:0);
        int b11 = (Q==0)?xp1:((Q>=2)?g1[1]:0);
        int b12 = (Q>=2)?g1[2]:0, b13 = (Q>=2)?g1[3]:0;

        do_cell(A3, bs3, b30, b31, b32, b33, cc3, g3, aL, aH, h3o);
        do_cell(A2, bs2, b20, b21, b22, b23, cc2, g2, aL, aH, h2o);
        do_cell(A1, bs1, b10, b11, b12, b13, cc1, g1, aL, aH, h1o);

        xc = xf; xf = xn;
    }

    // ---------- epilogue (drain): cell3(254),cell2(255); cell3(255) ----------
    {
        int b30 = (Q<2)?g2[0]:g3[0], b31 = (Q<2)?g2[1]:g3[1];
        int b32 = (Q<2)?g2[2]:g3[2], b33 = (Q<2)?g2[3]:g3[3];
        int b20 = (Q<2)?g1[0]:g2[0], b21 = (Q<2)?g1[1]:g2[1];
        int b22 = (Q<2)?g1[2]:g2[2], b23 = (Q<2)?g1[3]:g2[3];
        do_cell(A3, bs3, b30, b31, b32, b33, cc3, g3, aL, aH, h3o);
        do_cell(A2, bs2, b20, b21, b22, b23, cc2, g2, aL, aH, h2o);
    }
    {
        int b30 = (Q<2)?g2[0]:g3[0], b31 = (Q<2)?g2[1]:g3[1];
        int b32 = (Q<2)?g2[2]:g3[2], b33 = (Q<2)?g2[3]:g3[3];
        do_cell(A3, bs3, b30, b31, b32, b33, cc3, g3, aL, aH, h3o);
    }

    // lane 16Q+n holds h3[unit 4Q+r][batch n]
    {
        float4v ho = {h3o[0], h3o[1], h3o[2], h3o[3]};
        *(float4v*)&p.hout[(size_t)(b0 + n) * 32 + dir * HID + 4 * Q] = ho;
    }
}

__global__ void out_proj_kernel(const float* __restrict__ ws,
                                const float* __restrict__ Wout,
                                const float* __restrict__ bout,
                                float* __restrict__ out, int B)
{
    int idx = blockIdx.x * blockDim.x + threadIdx.x;
    if (idx >= B * 4) return;
    int b = idx >> 2, o = idx & 3;
    float acc = bout[o];
    const float* h = ws + (size_t)b * 32;
    const float* w = Wout + o * 32;
#pragma unroll
    for (int m = 0; m < 32; ++m) acc = fmaf(h[m], w[m], acc);
    out[idx] = acc;
}

extern "C" void kernel_launch(void* const* d_in, const int* in_sizes, int n_in,
                              void* d_out, int out_size, void* d_ws, size_t ws_size,
                              hipStream_t stream)
{
    const int B = in_sizes[0] / (T_LEN * D_IN); // 4096

    Params p;
    for (int s = 0; s < 6; ++s) {
        p.c[s].Wih = (const float*)d_in[1 + 4 * s];
        p.c[s].Whh = (const float*)d_in[2 + 4 * s];
        p.c[s].bih = (const float*)d_in[3 + 4 * s];
        p.c[s].bhh = (const float*)d_in[4 + 4 * s];
    }
    p.y = (const float*)d_in[0];
    p.hout = (float*)d_ws;

    const int tiles = (B / 16) * 2;          // 16 chains per wave, both dirs
    lstm_chain_kernel<<<tiles, 64, 0, stream>>>(p);

    const float* Wout = (const float*)d_in[25];
    const float* bout = (const float*)d_in[26];
    out_proj_kernel<<<(B * 4 + 255) / 256, 256, 0, stream>>>(
        (const float*)d_ws, Wout, bout, (float*)d_out, B);
}

// Round 9
// 315.209 us; speedup vs baseline: 1.1967x; 1.1185x over previous
//
#include <hip/hip_runtime.h>

#define T_LEN 256
#define D_IN 4
#define HID 16
#define NTHREADS 192

typedef _Float16 half8 __attribute__((ext_vector_type(8)));
typedef __fp16 cvt2_t __attribute__((ext_vector_type(2)));
typedef float float4v __attribute__((ext_vector_type(4)));

struct CellW { const float *Wih, *Whh, *bih, *bhh; };
struct Params { CellW c[6]; const float* y; float* hout; };

__device__ __forceinline__ float fexp2(float x) { return __builtin_amdgcn_exp2f(x); }
__device__ __forceinline__ float frcp(float x)  { return __builtin_amdgcn_rcpf(x); }
__device__ __forceinline__ int bperm(int a, int v) { return __builtin_amdgcn_ds_bpermute(a, v); }
__device__ __forceinline__ int packh(float a, float b) {
    cvt2_t p = __builtin_amdgcn_cvt_pkrtz(a, b);
    return __builtin_bit_cast(int, p);
}

#define MFMA(a, b, c) __builtin_amdgcn_mfma_f32_16x16x32_f16(a, b, c, 0, 0, 0)

// preacts -log2e-scaled (g gate: -2log2e), scale folded into A/bias.
__device__ __forceinline__ void cell_act(const float4v& pi, const float4v& pf,
                                         const float4v& pg, const float4v& po,
                                         float4v& c, float h[4]) {
#pragma unroll
    for (int r = 0; r < 4; ++r) {
        float i = frcp(1.f + fexp2(pi[r]));
        float f = frcp(1.f + fexp2(pf[r]));
        float g = fmaf(2.f, frcp(1.f + fexp2(pg[r])), -1.f);
        float o = frcp(1.f + fexp2(po[r]));
        float cn = fmaf(f, c[r], i * g);
        c[r] = cn;
        float th = fmaf(-2.f, frcp(1.f + fexp2(cn * 2.8853900817779268f)), 1.f);
        h[r] = o * th;
    }
}

// 4 gate MFMAs + activation + pack + bperm gather (recurrence for next step).
__device__ __forceinline__ void do_cell(const half8* A, const float4v* bs,
                                        int bd0, int bd1, int bd2, int bd3,
                                        float4v& c, int g[4], int aL, int aH,
                                        float h[4], int& d0, int& d1) {
    int4 bi = {bd0, bd1, bd2, bd3};
    half8 b = __builtin_bit_cast(half8, bi);
    float4v pi = MFMA(A[0], b, bs[0]);
    float4v pf = MFMA(A[1], b, bs[1]);
    float4v pg = MFMA(A[2], b, bs[2]);
    float4v po = MFMA(A[3], b, bs[3]);
    cell_act(pi, pf, pg, po, c, h);
    d0 = packh(h[0], h[1]);
    d1 = packh(h[2], h[3]);
    g[0] = bperm(aL, d0);
    g[1] = bperm(aL, d1);
    g[2] = bperm(aH, d0);
    g[3] = bperm(aH, d1);
}

// Block = 3 waves = 3 layers of one 16-chain tile, software-pipelined with a
// 1-round skew. h crosses waves via double-buffered LDS; x fully preloaded.
__global__ void __launch_bounds__(NTHREADS)
lstm_chain_kernel(Params p)
{
    // x slab: [t][chain] int2 (4 halfs) = 32KB. h slabs: [cell0/1][parity],
    // 16 cols * 48B (pad: 2-way conflicts max, 16B-aligned int4 reads).
    __shared__ int lds_x[T_LEN * 32];
    __shared__ int lds_h[2][2][192];

    const int w   = threadIdx.x >> 6;    // wave = layer (0,1,2)
    const int L   = threadIdx.x & 63;
    const int tid = blockIdx.x;
    const int dir = tid & 1;
    const int b0  = (tid >> 1) * 16;
    const int n   = L & 15;              // batch col
    const int Q   = L >> 4;

    const CellW cw = p.c[dir * 3 + w];
    const float LOG2E = 1.4426950408889634f;

    // ---- A-frags + bias for THIS wave's cell ----
    half8 A[4];
    float4v bs[4];
#pragma unroll
    for (int g = 0; g < 4; ++g) {
        const float s = (g == 2) ? -2.f * LOG2E : -LOG2E;
        const int row = g * 16 + n;
        half8 a;
#pragma unroll
        for (int j = 0; j < 8; ++j) {
            int k = Q * 8 + j;
            float v;
            if (w == 0) {
                if (k < D_IN)    v = cw.Wih[row * D_IN + k];
                else if (k < 16) v = 0.f;
                else             v = cw.Whh[row * 16 + (k - 16)];
            } else {
                v = (k < 16) ? cw.Wih[row * 16 + k] : cw.Whh[row * 16 + (k - 16)];
            }
            a[j] = (_Float16)(v * s);
        }
        A[g] = a;
        const int u0 = g * 16 + 4 * Q;
        float4 bi = *(const float4*)&cw.bih[u0];
        float4 bh = *(const float4*)&cw.bhh[u0];
        bs[g] = (float4v){(bi.x+bh.x)*s, (bi.y+bh.y)*s, (bi.z+bh.z)*s, (bi.w+bh.w)*s};
    }

    // ---- preload x for the whole tile (direction-adjusted) ----
    {
        const float* ybase = p.y + (size_t)b0 * (T_LEN * D_IN);
        for (int idx = threadIdx.x; idx < 16 * T_LEN; idx += NTHREADS) {
            const int c = idx >> 8, t = idx & 255;
            const int tt = dir ? (T_LEN - 1 - t) : t;
            float4 v = *(const float4*)(ybase + ((size_t)c * T_LEN + tt) * D_IN);
            lds_x[t * 32 + c * 2]     = packh(v.x, v.y);
            lds_x[t * 32 + c * 2 + 1] = packh(v.z, v.w);
        }
    }

    // bpermute source addresses for own-recurrence gather (round-8 layout)
    const int aL = 4 * ((Q & 1) * 32 + n);
    const int aH = aL + 64;

    float4v cc = {0.f, 0.f, 0.f, 0.f};
    int g[4] = {0, 0, 0, 0};
    float h[4];
    int d0 = 0, d1 = 0;

#pragma unroll 1
    for (int s = 0; s < T_LEN + 2; ++s) {
        __syncthreads();
        const bool on = (w == 0) ? (s < T_LEN)
                      : (w == 1) ? (s >= 1 && s < T_LEN + 1)
                                 : (s >= 2);
        if (!on) continue;

        int b0d, b1d, b2d, b3d;
        if (w == 0) {
            if (Q == 0) {
                int2 xv = *(const int2*)&lds_x[s * 32 + n * 2];
                b0d = xv.x; b1d = xv.y; b2d = 0; b3d = 0;
            } else if (Q == 1) {
                b0d = 0; b1d = 0; b2d = 0; b3d = 0;
            } else {
                b0d = g[0]; b1d = g[1]; b2d = g[2]; b3d = g[3];
            }
        } else {
            if (Q < 2) {
                int4 hv = *(const int4*)&lds_h[w - 1][(s - 1) & 1][n * 12 + Q * 4];
                b0d = hv.x; b1d = hv.y; b2d = hv.z; b3d = hv.w;
            } else {
                b0d = g[0]; b1d = g[1]; b2d = g[2]; b3d = g[3];
            }
        }

        do_cell(A, bs, b0d, b1d, b2d, b3d, cc, g, aL, aH, h, d0, d1);

        if (w < 2) {
            int2 hv = {d0, d1};
            *(int2*)&lds_h[w][s & 1][n * 12 + Q * 2] = hv;
        }
    }

    // wave 2 holds h3(T-1): lane 16Q+n has units 4Q+r, batch n
    if (w == 2) {
        float4v ho = {h[0], h[1], h[2], h[3]};
        *(float4v*)&p.hout[(size_t)(b0 + n) * 32 + dir * HID + 4 * Q] = ho;
    }
}

__global__ void out_proj_kernel(const float* __restrict__ ws,
                                const float* __restrict__ Wout,
                                const float* __restrict__ bout,
                                float* __restrict__ out, int B)
{
    int idx = blockIdx.x * blockDim.x + threadIdx.x;
    if (idx >= B * 4) return;
    int b = idx >> 2, o = idx & 3;
    float acc = bout[o];
    const float* h = ws + (size_t)b * 32;
    const float* w = Wout + o * 32;
#pragma unroll
    for (int m = 0; m < 32; ++m) acc = fmaf(h[m], w[m], acc);
    out[idx] = acc;
}

extern "C" void kernel_launch(void* const* d_in, const int* in_sizes, int n_in,
                              void* d_out, int out_size, void* d_ws, size_t ws_size,
                              hipStream_t stream)
{
    const int B = in_sizes[0] / (T_LEN * D_IN); // 4096

    Params p;
    for (int s = 0; s < 6; ++s) {
        p.c[s].Wih = (const float*)d_in[1 + 4 * s];
        p.c[s].Whh = (const float*)d_in[2 + 4 * s];
        p.c[s].bih = (const float*)d_in[3 + 4 * s];
        p.c[s].bhh = (const float*)d_in[4 + 4 * s];
    }
    p.y = (const float*)d_in[0];
    p.hout = (float*)d_ws;

    const int tiles = (B / 16) * 2;          // 16 chains per tile, both dirs
    lstm_chain_kernel<<<tiles, NTHREADS, 0, stream>>>(p);

    const float* Wout = (const float*)d_in[25];
    const float* bout = (const float*)d_in[26];
    out_proj_kernel<<<(B * 4 + 255) / 256, 256, 0, stream>>>(
        (const float*)d_ws, Wout, bout, (float*)d_out, B);
}